// Round 1
// baseline (93.102 us; speedup 1.0000x reference)
//
#include <hip/hip_runtime.h>

// Problem constants (fixed by setup_inputs: 40x40 grid, 4x1x80x80 structure map)
#define HIN  80
#define WIN  80
#define NB   4
#define HOUT 40
#define WOUT 40
#define NPTS (HOUT*WOUT)   // 1600
#define NHID 64

// ---------------------------------------------------------------------------
// Setup: build per-point row tables
//   A[p][h] =  x_p*W1[0][h] + y_p*W1[1][h] + s_mean[p]*W1[34][h] + base[h]
//   C[p][h] = -x_p*W1[0][h] - y_p*W1[1][h] + s_mean[p]*W1[35][h]
// where base[h] = b1[h] + sum_m mod_vec[m]*W1[2+m][h]
// s_mean: jax.image.resize(80->40, linear, antialias) then batch-mean.
// Antialiased triangle kernel at scale 0.5: weights {1,3,3,1}/8 over inputs
// {2o-1..2o+2}, renormalized at edges (o=0 -> [3,3,1]/7, o=39 -> [1,3,3]/7).
// ---------------------------------------------------------------------------
__global__ __launch_bounds__(64) void rpe_setup(
    const int* __restrict__ qmod, const int* __restrict__ kmod,
    const float* __restrict__ smap, const float* __restrict__ mode,
    const float* __restrict__ W1, const float* __restrict__ b1,
    float* __restrict__ Arows, float* __restrict__ Crows)
{
    __shared__ float wr0[NHID], wr1[NHID], wsi[NHID], wsj[NHID], sbase[NHID];
    __shared__ float smn[64], pxs[64], pys[64];
    const int t = threadIdx.x;

    wr0[t] = W1[t];
    wr1[t] = W1[NHID + t];
    wsi[t] = W1[34*NHID + t];
    wsj[t] = W1[35*NHID + t];
    const int q = qmod[0], k = kmod[0];
    float bacc = b1[t];
    #pragma unroll
    for (int m = 0; m < 16; ++m) bacc += mode[q*16 + m] * W1[(2 + m)*NHID + t];
    #pragma unroll
    for (int m = 0; m < 16; ++m) bacc += mode[k*16 + m] * W1[(18 + m)*NHID + t];
    sbase[t] = bacc;

    // one point per thread: s_mean + coords
    const int p  = blockIdx.x * 64 + t;
    const int oy = p / WOUT, ox = p % WOUT;
    float wy[4], wx[4]; int iy[4], ix[4];
    float wsy = 0.f, wsx = 0.f;
    #pragma unroll
    for (int d = 0; d < 4; ++d) {
        const float wv = (d == 0 || d == 3) ? 0.25f : 0.75f;
        const int yi = 2*oy + d - 1;
        const int xi = 2*ox + d - 1;
        iy[d] = yi < 0 ? 0 : (yi >= HIN ? HIN - 1 : yi);   // clamp (weight 0 anyway)
        ix[d] = xi < 0 ? 0 : (xi >= WIN ? WIN - 1 : xi);
        wy[d] = (yi >= 0 && yi < HIN) ? wv : 0.f;
        wx[d] = (xi >= 0 && xi < WIN) ? wv : 0.f;
        wsy += wy[d]; wsx += wx[d];
    }
    float acc = 0.f;
    for (int b = 0; b < NB; ++b) {
        const float* bp = smap + b*HIN*WIN;
        #pragma unroll
        for (int dy = 0; dy < 4; ++dy) {
            const float* rp = bp + iy[dy]*WIN;
            float rs = 0.f;
            #pragma unroll
            for (int dx = 0; dx < 4; ++dx) rs += wx[dx] * rp[ix[dx]];
            acc += wy[dy] * rs;
        }
    }
    const float smean = acc / (wsy * wsx * (float)NB);
    smn[t] = smean;
    pxs[t] = -0.5f + (float)ox * (1.0f/(float)(WOUT-1));
    pys[t] = -0.5f + (float)oy * (1.0f/(float)(HOUT-1));
    __syncthreads();

    // write A/C rows: thread t owns hidden index h=t -> coalesced stores
    const float w0 = wr0[t], w1v = wr1[t], wiv = wsi[t], wjv = wsj[t], bb = sbase[t];
    const int pbase = blockIdx.x * 64;
    for (int pl = 0; pl < 64; ++pl) {
        const float lin = pxs[pl]*w0 + pys[pl]*w1v;
        const float s   = smn[pl];
        Arows[(pbase + pl)*NHID + t] =  lin + s*wiv + bb;
        Crows[(pbase + pl)*NHID + t] = -lin + s*wjv;
    }
}

// ---------------------------------------------------------------------------
// Main: out[i,j] = relu(A[i] + C[j]) . W2 + b2
// 64x64 output tile per block, 256 threads, 4x4 register blocking,
// LDS rows padded to 68 floats (16B-aligned b128 reads, <=2-way bank alias).
// ---------------------------------------------------------------------------
__global__ __launch_bounds__(256) void rpe_bias(
    const float* __restrict__ Arows, const float* __restrict__ Crows,
    const float* __restrict__ W2, const float* __restrict__ b2,
    float* __restrict__ out)
{
    __shared__ float As[64][68];
    __shared__ float Cs[64][68];
    __shared__ float w2s[NHID];
    const int t  = threadIdx.x;
    const int bi = blockIdx.y, bj = blockIdx.x;

    #pragma unroll
    for (int k = 0; k < 4; ++k) {
        const int idx = t + k*256;          // 0..1023
        const int row = idx >> 4;           // 0..63
        const int col = (idx & 15) << 2;    // 0..60 step 4
        const float4 av = *(const float4*)(Arows + (size_t)(bi*64 + row)*NHID + col);
        const float4 cv = *(const float4*)(Crows + (size_t)(bj*64 + row)*NHID + col);
        *(float4*)&As[row][col] = av;
        *(float4*)&Cs[row][col] = cv;
    }
    if (t < NHID) w2s[t] = W2[t];
    __syncthreads();

    const int tx = t & 15;   // j = tx + 16*jj
    const int ty = t >> 4;   // i = ty + 16*ii

    float4 acc[4][4];
    #pragma unroll
    for (int ii = 0; ii < 4; ++ii)
        #pragma unroll
        for (int jj = 0; jj < 4; ++jj) acc[ii][jj] = make_float4(0.f, 0.f, 0.f, 0.f);

    #pragma unroll
    for (int h = 0; h < NHID; h += 4) {
        const float4 w4 = *(const float4*)&w2s[h];
        float4 a[4], c[4];
        #pragma unroll
        for (int ii = 0; ii < 4; ++ii) a[ii] = *(const float4*)&As[ty + ii*16][h];
        #pragma unroll
        for (int jj = 0; jj < 4; ++jj) c[jj] = *(const float4*)&Cs[tx + jj*16][h];
        #pragma unroll
        for (int ii = 0; ii < 4; ++ii) {
            #pragma unroll
            for (int jj = 0; jj < 4; ++jj) {
                float4 v;
                v.x = fmaxf(a[ii].x + c[jj].x, 0.f);
                v.y = fmaxf(a[ii].y + c[jj].y, 0.f);
                v.z = fmaxf(a[ii].z + c[jj].z, 0.f);
                v.w = fmaxf(a[ii].w + c[jj].w, 0.f);
                acc[ii][jj].x = fmaf(v.x, w4.x, acc[ii][jj].x);
                acc[ii][jj].y = fmaf(v.y, w4.y, acc[ii][jj].y);
                acc[ii][jj].z = fmaf(v.z, w4.z, acc[ii][jj].z);
                acc[ii][jj].w = fmaf(v.w, w4.w, acc[ii][jj].w);
            }
        }
    }

    const float bias2 = b2[0];
    #pragma unroll
    for (int ii = 0; ii < 4; ++ii) {
        const int i = bi*64 + ty + ii*16;
        float* orow = out + (size_t)i*NPTS + bj*64;
        #pragma unroll
        for (int jj = 0; jj < 4; ++jj) {
            const float4 a4 = acc[ii][jj];
            orow[tx + jj*16] = (a4.x + a4.y) + (a4.z + a4.w) + bias2;
        }
    }
}

extern "C" void kernel_launch(void* const* d_in, const int* in_sizes, int n_in,
                              void* d_out, int out_size, void* d_ws, size_t ws_size,
                              hipStream_t stream) {
    // inputs: 0:h 1:w 2:q_mod 3:k_mod 4:structure_map 5:mod_embed 6:W1 7:b1 8:W2 9:b2
    const int*   qm   = (const int*)d_in[2];
    const int*   km   = (const int*)d_in[3];
    const float* smap = (const float*)d_in[4];
    const float* mode = (const float*)d_in[5];
    const float* W1   = (const float*)d_in[6];
    const float* b1   = (const float*)d_in[7];
    const float* W2   = (const float*)d_in[8];
    const float* b2   = (const float*)d_in[9];
    float* out = (float*)d_out;

    float* Arows = (float*)d_ws;                 // 1600*64 f32
    float* Crows = Arows + (size_t)NPTS * NHID;  // 1600*64 f32 (total 819 KB)

    rpe_setup<<<NPTS/64, 64, 0, stream>>>(qm, km, smap, mode, W1, b1, Arows, Crows);
    rpe_bias<<<dim3(NPTS/64, NPTS/64), 256, 0, stream>>>(Arows, Crows, W2, b2, out);
}

// Round 2
// 90.493 us; speedup vs baseline: 1.0288x; 1.0288x over previous
//
#include <hip/hip_runtime.h>

// Problem constants (fixed by setup_inputs: 40x40 grid, 4x1x80x80 structure map)
#define HIN  80
#define WIN  80
#define NB   4
#define HOUT 40
#define WOUT 40
#define NPTS (HOUT*WOUT)   // 1600
#define NHID 64

// ---------------------------------------------------------------------------
// Fully fused: out[i,j] = relu(A[i] + C[j]) . W2 + b2   over a 64x64 tile.
//   A[p][h] =  x_p*W1[0][h] + y_p*W1[1][h] + s_mean[p]*W1[34][h] + base[h]
//   C[p][h] = -x_p*W1[0][h] - y_p*W1[1][h] + s_mean[p]*W1[35][h]
//   base[h] = b1[h] + sum_m mod_vec[m]*W1[2+m][h]
// s_mean: jax.image.resize(80->40, linear, antialias) batch-mean. Antialiased
// triangle at scale 0.5 = {1,3,3,1}/8 over {2o-1..2o+2}, edge-renormalized
// ([3,3,1]/7 at o=0, [1,3,3]/7 at o=39). Verified: bf16-exact (round 1).
//
// Phase 1 (per block, wave-specialized):
//   wave 0: load W1 rows 0,1,34,35 + W2 + compute base (mod_vec matvec)
//   wave 1: s_mean + coords for the 64 i-points (one point per lane)
//   wave 2: s_mean + coords for the 64 j-points
// Phase 2: all waves build As/Cs (h = lane -> stride-1 LDS, row broadcasts)
// Phase 3: 4x4 register-blocked pairwise relu-dot (same as round 1).
// ---------------------------------------------------------------------------
__global__ __launch_bounds__(256) void rpe_fused(
    const int* __restrict__ qmod, const int* __restrict__ kmod,
    const float* __restrict__ smap, const float* __restrict__ mode,
    const float* __restrict__ W1, const float* __restrict__ b1,
    const float* __restrict__ W2, const float* __restrict__ b2,
    float* __restrict__ out)
{
    __shared__ float As[64][68];
    __shared__ float Cs[64][68];
    __shared__ float w0s[NHID], w1s[NHID], wis[NHID], wjs[NHID], bases[NHID], w2s[NHID];
    __shared__ float sxi[64], syi[64], smi[64];
    __shared__ float sxj[64], syj[64], smj[64];

    const int t  = threadIdx.x;
    const int bi = blockIdx.y, bj = blockIdx.x;

    // ---------------- phase 1 (wave-specialized, branches wave-uniform) -----
    if (t < 64) {
        const int q = qmod[0], k = kmod[0];
        w0s[t] = W1[t];
        w1s[t] = W1[NHID + t];
        wis[t] = W1[34*NHID + t];
        wjs[t] = W1[35*NHID + t];
        w2s[t] = W2[t];
        float bacc = b1[t];
        #pragma unroll
        for (int m = 0; m < 16; ++m) bacc = fmaf(mode[q*16 + m], W1[(2 + m)*NHID + t], bacc);
        #pragma unroll
        for (int m = 0; m < 16; ++m) bacc = fmaf(mode[k*16 + m], W1[(18 + m)*NHID + t], bacc);
        bases[t] = bacc;
    } else if (t < 192) {
        const int isJ = (t >= 128) ? 1 : 0;
        const int idx = t - (isJ ? 128 : 64);
        const int p   = (isJ ? bj : bi) * 64 + idx;
        const int oy = p / WOUT, ox = p % WOUT;
        float wy[4], wx[4]; int iy[4], ix[4];
        float wsy = 0.f, wsx = 0.f;
        #pragma unroll
        for (int d = 0; d < 4; ++d) {
            const float wv = (d == 0 || d == 3) ? 0.25f : 0.75f;
            const int yi = 2*oy + d - 1;
            const int xi = 2*ox + d - 1;
            iy[d] = yi < 0 ? 0 : (yi >= HIN ? HIN - 1 : yi);
            ix[d] = xi < 0 ? 0 : (xi >= WIN ? WIN - 1 : xi);
            wy[d] = (yi >= 0 && yi < HIN) ? wv : 0.f;
            wx[d] = (xi >= 0 && xi < WIN) ? wv : 0.f;
            wsy += wy[d]; wsx += wx[d];
        }
        float acc = 0.f;
        #pragma unroll
        for (int b = 0; b < NB; ++b) {
            const float* bp = smap + b*HIN*WIN;
            #pragma unroll
            for (int dy = 0; dy < 4; ++dy) {
                const float* rp = bp + iy[dy]*WIN;
                float rs = 0.f;
                #pragma unroll
                for (int dx = 0; dx < 4; ++dx) rs = fmaf(wx[dx], rp[ix[dx]], rs);
                acc = fmaf(wy[dy], rs, acc);
            }
        }
        const float sm = acc / (wsy * wsx * (float)NB);
        const float x = -0.5f + (float)ox * (1.0f/(float)(WOUT-1));
        const float y = -0.5f + (float)oy * (1.0f/(float)(HOUT-1));
        if (isJ) { sxj[idx] = x; syj[idx] = y; smj[idx] = sm; }
        else     { sxi[idx] = x; syi[idx] = y; smi[idx] = sm; }
    }
    __syncthreads();

    // ---------------- phase 2: build As/Cs --------------------------------
    {
        const int h = t & 63;       // lane -> hidden index (stride-1 LDS writes)
        const int g = t >> 6;       // wave id -> row group (wave-uniform rows)
        const float w0 = w0s[h], w1v = w1s[h], wiv = wis[h], wjv = wjs[h], bb = bases[h];
        #pragma unroll
        for (int r = 0; r < 16; ++r) {
            const int row = g*16 + r;
            As[row][h] = fmaf(sxi[row], w0, fmaf(syi[row], w1v, fmaf(smi[row], wiv, bb)));
            Cs[row][h] = fmaf(smj[row], wjv, -fmaf(sxj[row], w0, syj[row] * w1v));
        }
    }
    __syncthreads();

    // ---------------- phase 3: pairwise relu-dot --------------------------
    const int tx = t & 15;   // j = tx + 16*jj
    const int ty = t >> 4;   // i = ty + 16*ii
    const float bias2 = b2[0];

    float4 acc[4][4];
    #pragma unroll
    for (int ii = 0; ii < 4; ++ii)
        #pragma unroll
        for (int jj = 0; jj < 4; ++jj) acc[ii][jj] = make_float4(0.f, 0.f, 0.f, 0.f);

    #pragma unroll
    for (int h = 0; h < NHID; h += 4) {
        const float4 w4 = *(const float4*)&w2s[h];
        float4 a[4], c[4];
        #pragma unroll
        for (int ii = 0; ii < 4; ++ii) a[ii] = *(const float4*)&As[ty + ii*16][h];
        #pragma unroll
        for (int jj = 0; jj < 4; ++jj) c[jj] = *(const float4*)&Cs[tx + jj*16][h];
        #pragma unroll
        for (int ii = 0; ii < 4; ++ii) {
            #pragma unroll
            for (int jj = 0; jj < 4; ++jj) {
                float4 v;
                v.x = fmaxf(a[ii].x + c[jj].x, 0.f);
                v.y = fmaxf(a[ii].y + c[jj].y, 0.f);
                v.z = fmaxf(a[ii].z + c[jj].z, 0.f);
                v.w = fmaxf(a[ii].w + c[jj].w, 0.f);
                acc[ii][jj].x = fmaf(v.x, w4.x, acc[ii][jj].x);
                acc[ii][jj].y = fmaf(v.y, w4.y, acc[ii][jj].y);
                acc[ii][jj].z = fmaf(v.z, w4.z, acc[ii][jj].z);
                acc[ii][jj].w = fmaf(v.w, w4.w, acc[ii][jj].w);
            }
        }
    }

    #pragma unroll
    for (int ii = 0; ii < 4; ++ii) {
        const int i = bi*64 + ty + ii*16;
        float* orow = out + (size_t)i*NPTS + bj*64;
        #pragma unroll
        for (int jj = 0; jj < 4; ++jj) {
            const float4 a4 = acc[ii][jj];
            orow[tx + jj*16] = (a4.x + a4.y) + (a4.z + a4.w) + bias2;
        }
    }
}

extern "C" void kernel_launch(void* const* d_in, const int* in_sizes, int n_in,
                              void* d_out, int out_size, void* d_ws, size_t ws_size,
                              hipStream_t stream) {
    // inputs: 0:h 1:w 2:q_mod 3:k_mod 4:structure_map 5:mod_embed 6:W1 7:b1 8:W2 9:b2
    const int*   qm   = (const int*)d_in[2];
    const int*   km   = (const int*)d_in[3];
    const float* smap = (const float*)d_in[4];
    const float* mode = (const float*)d_in[5];
    const float* W1   = (const float*)d_in[6];
    const float* b1   = (const float*)d_in[7];
    const float* W2   = (const float*)d_in[8];
    const float* b2   = (const float*)d_in[9];
    float* out = (float*)d_out;
    (void)d_ws; (void)ws_size;

    rpe_fused<<<dim3(NPTS/64, NPTS/64), 256, 0, stream>>>(
        qm, km, smap, mode, W1, b1, W2, b2, out);
}

// Round 3
// 86.441 us; speedup vs baseline: 1.0771x; 1.0469x over previous
//
#include <hip/hip_runtime.h>

// Problem constants (fixed by setup_inputs: 40x40 grid, 4x1x80x80 structure map)
#define HIN  80
#define WIN  80
#define NB   4
#define HOUT 40
#define WOUT 40
#define NPTS (HOUT*WOUT)   // 1600
#define NHID 64

// ---------------------------------------------------------------------------
// out[i,j] = relu(A[i]+C[j]).W2 + b2 over 64x64 tiles, fully fused.
//   A[p][h] =  x_p*W1[0][h] + y_p*W1[1][h] + s_mean[p]*W1[34][h] + base[h]
//   C[p][h] = -x_p*W1[0][h] - y_p*W1[1][h] + s_mean[p]*W1[35][h]
//   base[h] = b1[h] + sum_m mod_vec[m]*W1[2+m][h]
//
// Round-3 rewrite of phase 3 via the abs identity:
//   relu(x)*W2[h] = x*w2h + |x|*w2h,   w2h = 0.5*W2[h]  (exact pow2 scale)
//   sum_h (a+c)*w2h = linA[i] + linC[j]          (rank-1, precomputed per row)
//   => out[i,j] = b2 + linA[i] + linC[j] + sum_h |a_i[h]+c_j[h]|*w2h
// Inner loop is now 2 VALU/pair/h (v_add + v_fma with abs() modifier, w2h in
// SGPR via uniform s_load) vs 3 before, and w2 leaves LDS.
//
// s_mean: jax.image.resize 80->40 linear+antialias = {1,3,3,1}/8 separable,
// edge-renormalized ([3,3,1]/7). Verified bf16-exact in rounds 1-2.
// ---------------------------------------------------------------------------
__global__ __launch_bounds__(256) void rpe_fused(
    const int* __restrict__ qmod, const int* __restrict__ kmod,
    const float* __restrict__ smap, const float* __restrict__ mode,
    const float* __restrict__ W1, const float* __restrict__ b1,
    const float* __restrict__ W2, const float* __restrict__ b2,
    float* __restrict__ out)
{
    __shared__ float As[64][68];
    __shared__ float Cs[64][68];
    __shared__ float w0s[NHID], w1s[NHID], wis[NHID], wjs[NHID], bases[NHID];
    __shared__ float sxi[64], syi[64], smi[64];
    __shared__ float sxj[64], syj[64], smj[64];
    __shared__ float linA[64], linC[64];

    const int t  = threadIdx.x;
    const int bi = blockIdx.y, bj = blockIdx.x;

    // ---------------- phase 1 (wave-specialized, wave-uniform branches) -----
    if (t < 64) {
        const int q = qmod[0], k = kmod[0];
        w0s[t] = W1[t];
        w1s[t] = W1[NHID + t];
        wis[t] = W1[34*NHID + t];
        wjs[t] = W1[35*NHID + t];
        float bacc = b1[t];
        #pragma unroll
        for (int m = 0; m < 16; ++m) bacc = fmaf(mode[q*16 + m], W1[(2 + m)*NHID + t], bacc);
        #pragma unroll
        for (int m = 0; m < 16; ++m) bacc = fmaf(mode[k*16 + m], W1[(18 + m)*NHID + t], bacc);
        bases[t] = bacc;
    } else if (t < 192) {
        const int isJ = (t >= 128) ? 1 : 0;
        const int idx = t - (isJ ? 128 : 64);
        const int p   = (isJ ? bj : bi) * 64 + idx;
        const int oy = p / WOUT, ox = p % WOUT;
        float wy[4], wx[4]; int iy[4], ix[4];
        float wsy = 0.f, wsx = 0.f;
        #pragma unroll
        for (int d = 0; d < 4; ++d) {
            const float wv = (d == 0 || d == 3) ? 0.25f : 0.75f;
            const int yi = 2*oy + d - 1;
            const int xi = 2*ox + d - 1;
            iy[d] = yi < 0 ? 0 : (yi >= HIN ? HIN - 1 : yi);
            ix[d] = xi < 0 ? 0 : (xi >= WIN ? WIN - 1 : xi);
            wy[d] = (yi >= 0 && yi < HIN) ? wv : 0.f;
            wx[d] = (xi >= 0 && xi < WIN) ? wv : 0.f;
            wsy += wy[d]; wsx += wx[d];
        }
        float acc = 0.f;
        #pragma unroll
        for (int b = 0; b < NB; ++b) {
            const float* bp = smap + b*HIN*WIN;
            #pragma unroll
            for (int dy = 0; dy < 4; ++dy) {
                const float* rp = bp + iy[dy]*WIN;
                float rs = 0.f;
                #pragma unroll
                for (int dx = 0; dx < 4; ++dx) rs = fmaf(wx[dx], rp[ix[dx]], rs);
                acc = fmaf(wy[dy], rs, acc);
            }
        }
        const float sm = acc / (wsy * wsx * (float)NB);
        const float x = -0.5f + (float)ox * (1.0f/(float)(WOUT-1));
        const float y = -0.5f + (float)oy * (1.0f/(float)(HOUT-1));
        if (isJ) { sxj[idx] = x; syj[idx] = y; smj[idx] = sm; }
        else     { sxi[idx] = x; syi[idx] = y; smi[idx] = sm; }
    }
    __syncthreads();

    // ---------------- phase 2: build As/Cs (h = lane, stride-1 LDS) --------
    {
        const int h = t & 63;
        const int g = t >> 6;
        const float w0 = w0s[h], w1v = w1s[h], wiv = wis[h], wjv = wjs[h], bb = bases[h];
        #pragma unroll
        for (int r = 0; r < 16; ++r) {
            const int row = g*16 + r;
            As[row][h] = fmaf(sxi[row], w0, fmaf(syi[row], w1v, fmaf(smi[row], wiv, bb)));
            Cs[row][h] = fmaf(smj[row], wjv, -fmaf(sxj[row], w0, syj[row] * w1v));
        }
    }
    __syncthreads();

    // ---------------- phase 2b: rank-1 row terms (threads 0..127) ----------
    // linA[p] = sum_h As[p][h]*w2h ; linC[p] = sum_h Cs[p][h]*w2h
    if (t < 128) {
        const int p = t & 63;
        const float* row = (t < 64) ? &As[p][0] : &Cs[p][0];
        float s = 0.f;
        #pragma unroll
        for (int h = 0; h < NHID; h += 4) {
            const float4 r4 = *(const float4*)(row + h);
            s = fmaf(r4.x, 0.5f*W2[h+0],
                fmaf(r4.y, 0.5f*W2[h+1],
                fmaf(r4.z, 0.5f*W2[h+2],
                fmaf(r4.w, 0.5f*W2[h+3], s))));
        }
        if (t < 64) linA[p] = s; else linC[p] = s;
    }
    // no barrier yet: main loop doesn't read linA/linC until after next sync

    // ---------------- phase 3: pairwise |a+c| dot -------------------------
    const int tx = t & 15;   // j = tx + 16*jj
    const int ty = t >> 4;   // i = ty + 16*ii

    float4 acc[4][4];
    #pragma unroll
    for (int ii = 0; ii < 4; ++ii)
        #pragma unroll
        for (int jj = 0; jj < 4; ++jj) acc[ii][jj] = make_float4(0.f, 0.f, 0.f, 0.f);

    #pragma unroll
    for (int h = 0; h < NHID; h += 4) {
        // uniform -> scalar loads into SGPRs; v_fma takes SGPR operand
        const float w2x = 0.5f*W2[h+0], w2y = 0.5f*W2[h+1];
        const float w2z = 0.5f*W2[h+2], w2w = 0.5f*W2[h+3];
        float4 a[4], c[4];
        #pragma unroll
        for (int ii = 0; ii < 4; ++ii) a[ii] = *(const float4*)&As[ty + ii*16][h];
        #pragma unroll
        for (int jj = 0; jj < 4; ++jj) c[jj] = *(const float4*)&Cs[tx + jj*16][h];
        #pragma unroll
        for (int ii = 0; ii < 4; ++ii) {
            #pragma unroll
            for (int jj = 0; jj < 4; ++jj) {
                acc[ii][jj].x = fmaf(fabsf(a[ii].x + c[jj].x), w2x, acc[ii][jj].x);
                acc[ii][jj].y = fmaf(fabsf(a[ii].y + c[jj].y), w2y, acc[ii][jj].y);
                acc[ii][jj].z = fmaf(fabsf(a[ii].z + c[jj].z), w2z, acc[ii][jj].z);
                acc[ii][jj].w = fmaf(fabsf(a[ii].w + c[jj].w), w2w, acc[ii][jj].w);
            }
        }
    }

    __syncthreads();   // linA/linC ready (phase 2b), everyone past main loop

    const float bias2 = b2[0];
    float la[4], lc[4];
    #pragma unroll
    for (int ii = 0; ii < 4; ++ii) la[ii] = linA[ty + ii*16];
    #pragma unroll
    for (int jj = 0; jj < 4; ++jj) lc[jj] = linC[tx + jj*16];

    #pragma unroll
    for (int ii = 0; ii < 4; ++ii) {
        const int i = bi*64 + ty + ii*16;
        float* orow = out + (size_t)i*NPTS + bj*64;
        #pragma unroll
        for (int jj = 0; jj < 4; ++jj) {
            const float4 a4 = acc[ii][jj];
            orow[tx + jj*16] = ((a4.x + a4.y) + (a4.z + a4.w))
                             + (la[ii] + lc[jj]) + bias2;
        }
    }
}

extern "C" void kernel_launch(void* const* d_in, const int* in_sizes, int n_in,
                              void* d_out, int out_size, void* d_ws, size_t ws_size,
                              hipStream_t stream) {
    // inputs: 0:h 1:w 2:q_mod 3:k_mod 4:structure_map 5:mod_embed 6:W1 7:b1 8:W2 9:b2
    const int*   qm   = (const int*)d_in[2];
    const int*   km   = (const int*)d_in[3];
    const float* smap = (const float*)d_in[4];
    const float* mode = (const float*)d_in[5];
    const float* W1   = (const float*)d_in[6];
    const float* b1   = (const float*)d_in[7];
    const float* W2   = (const float*)d_in[8];
    const float* b2   = (const float*)d_in[9];
    float* out = (float*)d_out;
    (void)d_ws; (void)ws_size;

    rpe_fused<<<dim3(NPTS/64, NPTS/64), 256, 0, stream>>>(
        qm, km, smap, mode, W1, b1, W2, b2, out);
}